// Round 6
// baseline (89.755 us; speedup 1.0000x reference)
//
#include <hip/hip_runtime.h>
#include <cstddef>
#include <cstdint>

// KPNextBlock: M=N=50000, H=32, C=128, K=15, GROUPS=8, CPG=16 -> K*CPG=240,
// RADIUS=1.2, SIGMA=0.9.
namespace {
constexpr int H_N    = 32;
constexpr int C_F    = 128;
constexpr int K_P    = 15;
constexpr int MODC   = 240;
constexpr int ROWS_B = 64;    // rows per MLP block (64 -> 5 blocks/CU, 20 waves/CU)
}

typedef __attribute__((ext_vector_type(8))) short short8v;
typedef __attribute__((ext_vector_type(4))) float f32x4;

__device__ __forceinline__ unsigned short bf16_hi(float f) {
    unsigned u = __builtin_bit_cast(unsigned, f);
    unsigned r = (u + 0x7FFFu + ((u >> 16) & 1u)) >> 16;
    return (unsigned short)r;
}
__device__ __forceinline__ float bf16_f(unsigned short h) {
    unsigned u = ((unsigned)h) << 16;
    return __builtin_bit_cast(float, u);
}

__device__ __forceinline__ f32x4 mfma3(short8v ah, short8v al, short8v bh, short8v bl, f32x4 c) {
    // (ah+al)*(bh+bl) dropping al*bl: error ~2^-18 relative -> fp32-class.
    c = __builtin_amdgcn_mfma_f32_16x16x32_bf16(ah, bl, c, 0, 0, 0);
    c = __builtin_amdgcn_mfma_f32_16x16x32_bf16(al, bh, c, 0, 0, 0);
    c = __builtin_amdgcn_mfma_f32_16x16x32_bf16(ah, bh, c, 0, 0, 0);
    return c;
}

// ---------------------------------------------------------------------------
// Pre-pass: split w1 [128][128] and w2 [128][240] into bf16 hi/lo, TRANSPOSED
// to [col][k] so MFMA B-fragments are 16B-contiguous per lane.
// ---------------------------------------------------------------------------
__global__ __launch_bounds__(256)
void split_w_kernel(const float* __restrict__ w1, const float* __restrict__ w2,
                    unsigned short* __restrict__ w1t_hi, unsigned short* __restrict__ w1t_lo,
                    unsigned short* __restrict__ w2t_hi, unsigned short* __restrict__ w2t_lo)
{
    const int i = blockIdx.x * 256 + threadIdx.x;
    if (i < C_F * C_F) {
        const int c = i >> 7, j = i & 127;          // w1[c][j]
        const float v = w1[i];
        const unsigned short h = bf16_hi(v);
        w1t_hi[j * C_F + c] = h;
        w1t_lo[j * C_F + c] = bf16_hi(v - bf16_f(h));
    }
    const int i2 = i - C_F * C_F;
    if (i2 >= 0 && i2 < C_F * MODC) {
        const int c = i2 / MODC, j = i2 - c * MODC; // w2[c][j]
        const float v = w2[i2];
        const unsigned short h = bf16_hi(v);
        w2t_hi[j * C_F + c] = h;
        w2t_lo[j * C_F + c] = bf16_hi(v - bf16_f(h));
    }
}

// ---------------------------------------------------------------------------
// Kernel 1: MLP. Per block of 64 rows, 4 waves (one col-group each):
//   stage x (bf16 hi/lo, XOR-swizzled LDS, 32KB) -> MFMA phase1 (h) ->
//   writeback -> MFMA phase2 -> sigmoid -> mod fp32 to global.
// Wave owns 4 row-tiles x {2 col-tiles (phase1) | ~4 col-tiles (phase2)}.
// launch_bounds(256,5): 5 blocks/CU (LDS 32KB) -> 20 waves/CU; VGPR cap ~102
// (compiler needs 84 -> spill-free, round-4/5 verified).
// ---------------------------------------------------------------------------
__global__ __launch_bounds__(256, 5)
void mlp_kernel(const float* __restrict__ s_feats,
                const unsigned short* __restrict__ w1t_hi,
                const unsigned short* __restrict__ w1t_lo,
                const unsigned short* __restrict__ w2t_hi,
                const unsigned short* __restrict__ w2t_lo,
                const float* __restrict__ b1,
                float* __restrict__ modg,
                int m_base, int rows_total)
{
    __shared__ __align__(16) unsigned char lds_raw[32768];   // xhi 16KB | xlo 16KB

    const int t  = threadIdx.x;
    const int r0 = blockIdx.x * ROWS_B;
    int rows = rows_total - r0; if (rows > ROWS_B) rows = ROWS_B;

    // ---- stage x: fp32 -> bf16 hi/lo, swizzled LDS [row][k] ----
    {
        const int row = t >> 2;          // 0..63
        const int k0  = (t & 3) << 5;    // 0,32,64,96
        const float4* src = reinterpret_cast<const float4*>(
            s_feats + (size_t)(m_base + r0 + row) * C_F + k0);
        #pragma unroll
        for (int s = 0; s < 4; ++s) {
            float v[8];
            if (row < rows) {
                const float4 a = src[s * 2 + 0];
                const float4 b = src[s * 2 + 1];
                v[0] = a.x; v[1] = a.y; v[2] = a.z; v[3] = a.w;
                v[4] = b.x; v[5] = b.y; v[6] = b.z; v[7] = b.w;
            } else {
                #pragma unroll
                for (int e = 0; e < 8; ++e) v[e] = 0.f;
            }
            short8v hv, lv;
            #pragma unroll
            for (int e = 0; e < 8; ++e) {
                const unsigned short h = bf16_hi(v[e]);
                hv[e] = (short)h;
                lv[e] = (short)bf16_hi(v[e] - bf16_f(h));
            }
            const unsigned addr = (unsigned)((row * 256 + (k0 + s * 8) * 2) ^ ((row & 7) << 4));
            *reinterpret_cast<short8v*>(lds_raw + addr)         = hv;
            *reinterpret_cast<short8v*>(lds_raw + 16384 + addr) = lv;
        }
    }
    __syncthreads();

    const int wave = t >> 6, lane = t & 63;
    const int wc = wave;           // col group 0..3
    const int g  = lane >> 4;      // k-block
    const int ln = lane & 15;

    // ---- phase 1: h = leaky_relu(x @ w1 + b1) ----
    f32x4 acc1[4][2];
    #pragma unroll
    for (int cti = 0; cti < 2; ++cti) {
        const float b = b1[(wc + 4 * cti) * 16 + ln];
        #pragma unroll
        for (int rt = 0; rt < 4; ++rt) acc1[rt][cti] = f32x4{b, b, b, b};
    }
    #pragma unroll
    for (int ks = 0; ks < 4; ++ks) {
        short8v ah[4], al[4];
        #pragma unroll
        for (int rt = 0; rt < 4; ++rt) {
            const int row = rt * 16 + ln;
            const unsigned addr = (unsigned)((row * 256 + (ks * 32 + g * 8) * 2) ^ ((row & 7) << 4));
            ah[rt] = *reinterpret_cast<const short8v*>(lds_raw + addr);
            al[rt] = *reinterpret_cast<const short8v*>(lds_raw + 16384 + addr);
        }
        #pragma unroll
        for (int cti = 0; cti < 2; ++cti) {
            const int col = (wc + 4 * cti) * 16 + ln;
            const size_t off = (size_t)col * C_F + ks * 32 + g * 8;
            const short8v bh = *reinterpret_cast<const short8v*>(w1t_hi + off);
            const short8v bl = *reinterpret_cast<const short8v*>(w1t_lo + off);
            #pragma unroll
            for (int rt = 0; rt < 4; ++rt)
                acc1[rt][cti] = mfma3(ah[rt], al[rt], bh, bl, acc1[rt][cti]);
        }
    }
    __syncthreads();   // all waves done reading x before h overwrites it

    // ---- leaky_relu + bf16 split + writeback (C/D: col=ln, row=g*4+r) ----
    #pragma unroll
    for (int rt = 0; rt < 4; ++rt) {
        #pragma unroll
        for (int cti = 0; cti < 2; ++cti) {
            const int col = (wc + 4 * cti) * 16 + ln;
            #pragma unroll
            for (int r = 0; r < 4; ++r) {
                float v = acc1[rt][cti][r];
                v = v > 0.f ? v : 0.1f * v;
                const int row = rt * 16 + g * 4 + r;
                const unsigned short h = bf16_hi(v);
                const unsigned addr = (unsigned)((row * 256 + col * 2) ^ ((row & 7) << 4));
                *reinterpret_cast<unsigned short*>(lds_raw + addr)         = h;
                *reinterpret_cast<unsigned short*>(lds_raw + 16384 + addr) = bf16_hi(v - bf16_f(h));
            }
        }
    }
    __syncthreads();

    // ---- phase 2: mod = sigmoid(h @ w2) -> global ----
    f32x4 acc2[4][4];
    #pragma unroll
    for (int rt = 0; rt < 4; ++rt)
        #pragma unroll
        for (int cs = 0; cs < 4; ++cs) acc2[rt][cs] = f32x4{0.f, 0.f, 0.f, 0.f};

    #pragma unroll
    for (int ks = 0; ks < 4; ++ks) {
        short8v ah[4], al[4];
        #pragma unroll
        for (int rt = 0; rt < 4; ++rt) {
            const int row = rt * 16 + ln;
            const unsigned addr = (unsigned)((row * 256 + (ks * 32 + g * 8) * 2) ^ ((row & 7) << 4));
            ah[rt] = *reinterpret_cast<const short8v*>(lds_raw + addr);
            al[rt] = *reinterpret_cast<const short8v*>(lds_raw + 16384 + addr);
        }
        #pragma unroll
        for (int cs = 0; cs < 4; ++cs) {
            const int ctile = wc + 4 * cs;          // wave-uniform guard, static acc idx
            if (ctile < K_P) {
                const int col = ctile * 16 + ln;
                const size_t off = (size_t)col * C_F + ks * 32 + g * 8;
                const short8v bh = *reinterpret_cast<const short8v*>(w2t_hi + off);
                const short8v bl = *reinterpret_cast<const short8v*>(w2t_lo + off);
                #pragma unroll
                for (int rt = 0; rt < 4; ++rt)
                    acc2[rt][cs] = mfma3(ah[rt], al[rt], bh, bl, acc2[rt][cs]);
            }
        }
    }

    // sigmoid + store (chunk-local row index, fp32)
    #pragma unroll
    for (int rt = 0; rt < 4; ++rt) {
        #pragma unroll
        for (int cs = 0; cs < 4; ++cs) {
            const int ctile = wc + 4 * cs;
            if (ctile < K_P) {
                const int col = ctile * 16 + ln;
                #pragma unroll
                for (int r = 0; r < 4; ++r) {
                    const int row = rt * 16 + g * 4 + r;
                    if (row < rows) {
                        const float v = 1.f / (1.f + __expf(-acc2[rt][cs][r]));
                        modg[(size_t)(r0 + row) * MODC + col] = v;
                    }
                }
            }
        }
    }
}

// ---------------------------------------------------------------------------
// Kernel 2: geometry + sparse gather/accumulate. One wave (64 lanes) per query
// (round-2-verified structure: 12500 blocks -> latency hidden by TLP).
// ---------------------------------------------------------------------------
__global__ __launch_bounds__(256)
void kpconv_kernel(const float* __restrict__ q_pts,
                   const float* __restrict__ s_pts,
                   const float* __restrict__ s_feats,
                   const int* __restrict__ nbi,
                   const float* __restrict__ da_scale,
                   const float* __restrict__ weights,
                   const float* __restrict__ kp,
                   const float* __restrict__ mod,   // chunk-local [rows, 240]
                   float* __restrict__ out,
                   int m_base, int rows_total)
{
    const int t    = threadIdx.x;
    const int lane = t & 63;
    const int r    = blockIdx.x * 4 + (t >> 6);
    if (r >= rows_total) return;
    const int m = m_base + r;

    const float qx = q_pts[m * 3 + 0];
    const float qy = q_pts[m * 3 + 1];
    const float qz = q_pts[m * 3 + 2];
    const float das = da_scale[m];

    int   idx = 0, nn = 0;
    float fl  = 0.f;
    if (lane < H_N) {
        idx = nbi[(size_t)m * H_N + lane];
        const float sx = s_pts[idx * 3 + 0];
        const float sy = s_pts[idx * 3 + 1];
        const float sz = s_pts[idx * 3 + 2];
        // plain fp32 (no fma contraction) to match numpy rounding at argmin ties
        const float dx = __fsub_rn(sx, qx);
        const float dy = __fsub_rn(sy, qy);
        const float dz = __fsub_rn(sz, qz);
        const float dd = __fadd_rn(__fadd_rn(__fmul_rn(dx, dx), __fmul_rn(dy, dy)),
                                   __fmul_rn(dz, dz));
        // |kp| < 1.2 strictly => |d| >= 0.9 + 1.2*da implies infl == 0 exactly.
        const float reach = 0.9f + 1.2f * das;
        if (dd < reach * reach) {
            float best = 3.4e38f; int bi = 0;
            #pragma unroll
            for (int k = 0; k < K_P; ++k) {
                const float ex = __fsub_rn(dx, __fmul_rn(kp[k * 3 + 0], das));
                const float ey = __fsub_rn(dy, __fmul_rn(kp[k * 3 + 1], das));
                const float ez = __fsub_rn(dz, __fmul_rn(kp[k * 3 + 2], das));
                const float d2 = __fadd_rn(__fadd_rn(__fmul_rn(ex, ex), __fmul_rn(ey, ey)),
                                           __fmul_rn(ez, ez));
                if (d2 < best) { best = d2; bi = k; }
            }
            const float f = 1.f - sqrtf(best) / 0.9f;
            fl = fmaxf(f, 0.f);
            nn = bi;
        }
    }

    unsigned long long mask = __ballot(fl > 0.f);
    const int c0 = lane << 1;
    float2 acc = {0.f, 0.f};
    while (mask) {
        const int h = __builtin_ctzll(mask);
        mask &= mask - 1;
        const int   ih = __shfl(idx, h);
        const int   nh = __shfl(nn, h);
        const float fh = __shfl(fl, h);
        const float2 fv = *reinterpret_cast<const float2*>(s_feats + (size_t)ih * C_F + c0);
        const float2 wv = *reinterpret_cast<const float2*>(weights + nh * C_F + c0);
        const float  mv = mod[(size_t)r * MODC + nh * 16 + (lane >> 2)];
        const float  s  = fh * mv;
        acc.x = fmaf(fv.x * wv.x, s, acc.x);
        acc.y = fmaf(fv.y * wv.y, s, acc.y);
    }
    reinterpret_cast<float2*>(out + (size_t)m * C_F)[lane] = acc;
}

// ---------------------------------------------------------------------------
extern "C" void kernel_launch(void* const* d_in, const int* in_sizes, int n_in,
                              void* d_out, int out_size, void* d_ws, size_t ws_size,
                              hipStream_t stream)
{
    const float* q_pts  = (const float*)d_in[0];
    const float* s_pts  = (const float*)d_in[1];
    const float* s_feat = (const float*)d_in[2];
    const int*   nbi    = (const int*)d_in[3];
    const float* da     = (const float*)d_in[4];
    const float* wts    = (const float*)d_in[5];
    const float* w1     = (const float*)d_in[6];
    const float* b1     = (const float*)d_in[7];
    const float* w2     = (const float*)d_in[8];
    const float* kp     = (const float*)d_in[9];
    float* out = (float*)d_out;

    const int M = in_sizes[4];   // da_scale has M elements

    // workspace layout: split weights (184KB, 256B-aligned) then mod buffer
    unsigned short* w1t_hi = (unsigned short*)d_ws;
    unsigned short* w1t_lo = w1t_hi + C_F * C_F;
    unsigned short* w2t_hi = w1t_lo + C_F * C_F;
    unsigned short* w2t_lo = w2t_hi + C_F * MODC;
    size_t woff = ((size_t)(2 * C_F * C_F + 2 * C_F * MODC) * sizeof(unsigned short) + 255) & ~(size_t)255;
    float* mod = (float*)((char*)d_ws + woff);

    const int nsplit = (C_F * C_F + C_F * MODC + 255) / 256;
    split_w_kernel<<<dim3(nsplit), 256, 0, stream>>>(w1, w2, w1t_hi, w1t_lo, w2t_hi, w2t_lo);

    // mod needs M*240*4 = 48MB; chunk if workspace is smaller.
    size_t cap = (ws_size - woff) / ((size_t)MODC * sizeof(float));
    int chunk = (cap >= (size_t)M) ? M : (int)(cap & ~(size_t)63);
    if (chunk < 64) chunk = 64;

    for (int m0 = 0; m0 < M; m0 += chunk) {
        int rows = M - m0; if (rows > chunk) rows = chunk;
        mlp_kernel<<<dim3((rows + ROWS_B - 1) / ROWS_B), 256, 0, stream>>>(
            s_feat, w1t_hi, w1t_lo, w2t_hi, w2t_lo, b1, mod, m0, rows);
        kpconv_kernel<<<dim3((rows + 3) / 4), 256, 0, stream>>>(
            q_pts, s_pts, s_feat, nbi, da, wts, kp, mod, out, m0, rows);
    }
}

// Round 7
// 69.524 us; speedup vs baseline: 1.2910x; 1.2910x over previous
//
#include <hip/hip_runtime.h>
#include <cstddef>
#include <cstdint>

// KPNextBlock: M=N=50000, H=32, C=128, K=15, GROUPS=8, CPG=16 -> K*CPG=240,
// RADIUS=1.2, SIGMA=0.9.
namespace {
constexpr int H_N    = 32;
constexpr int C_F    = 128;
constexpr int K_P    = 15;
constexpr int MODC   = 240;
constexpr int ROWS_B = 64;    // rows per MLP block
}

typedef __attribute__((ext_vector_type(8))) short short8v;
typedef __attribute__((ext_vector_type(4))) float f32x4;

__device__ __forceinline__ unsigned short bf16_hi(float f) {
    unsigned u = __builtin_bit_cast(unsigned, f);
    unsigned r = (u + 0x7FFFu + ((u >> 16) & 1u)) >> 16;
    return (unsigned short)r;
}
__device__ __forceinline__ float bf16_f(unsigned short h) {
    unsigned u = ((unsigned)h) << 16;
    return __builtin_bit_cast(float, u);
}

__device__ __forceinline__ f32x4 mfma3(short8v ah, short8v al, short8v bh, short8v bl, f32x4 c) {
    // (ah+al)*(bh+bl) dropping al*bl: error ~2^-18 relative -> fp32-class.
    c = __builtin_amdgcn_mfma_f32_16x16x32_bf16(ah, bl, c, 0, 0, 0);
    c = __builtin_amdgcn_mfma_f32_16x16x32_bf16(al, bh, c, 0, 0, 0);
    c = __builtin_amdgcn_mfma_f32_16x16x32_bf16(ah, bh, c, 0, 0, 0);
    return c;
}

// ---------------------------------------------------------------------------
// Pre-pass: split w1 [128][128] and w2 [128][240] into bf16 hi/lo, TRANSPOSED
// to [col][k] so MFMA B-fragments are 16B-contiguous per lane.
// ---------------------------------------------------------------------------
__global__ __launch_bounds__(256)
void split_w_kernel(const float* __restrict__ w1, const float* __restrict__ w2,
                    unsigned short* __restrict__ w1t_hi, unsigned short* __restrict__ w1t_lo,
                    unsigned short* __restrict__ w2t_hi, unsigned short* __restrict__ w2t_lo)
{
    const int i = blockIdx.x * 256 + threadIdx.x;
    if (i < C_F * C_F) {
        const int c = i >> 7, j = i & 127;          // w1[c][j]
        const float v = w1[i];
        const unsigned short h = bf16_hi(v);
        w1t_hi[j * C_F + c] = h;
        w1t_lo[j * C_F + c] = bf16_hi(v - bf16_f(h));
    }
    const int i2 = i - C_F * C_F;
    if (i2 >= 0 && i2 < C_F * MODC) {
        const int c = i2 / MODC, j = i2 - c * MODC; // w2[c][j]
        const float v = w2[i2];
        const unsigned short h = bf16_hi(v);
        w2t_hi[j * C_F + c] = h;
        w2t_lo[j * C_F + c] = bf16_hi(v - bf16_f(h));
    }
}

// ---------------------------------------------------------------------------
// Kernel 1: MLP. Per block of 64 rows, 4 waves (one col-group each):
//   stage x (bf16 hi/lo, XOR-swizzled LDS, 32KB) -> MFMA phase1 (h) ->
//   writeback -> MFMA phase2 -> sigmoid -> mod bf16 to global.
// launch_bounds(256,2): VGPR cap 128 (empirical cap = 256/min_waves; the
// kernel needs ~84 -> SPILL-FREE. (256,5) capped at 48 and spilled 90MB).
// ---------------------------------------------------------------------------
__global__ __launch_bounds__(256, 2)
void mlp_kernel(const float* __restrict__ s_feats,
                const unsigned short* __restrict__ w1t_hi,
                const unsigned short* __restrict__ w1t_lo,
                const unsigned short* __restrict__ w2t_hi,
                const unsigned short* __restrict__ w2t_lo,
                const float* __restrict__ b1,
                unsigned short* __restrict__ modg,   // bf16 [rows][240]
                int m_base, int rows_total)
{
    __shared__ __align__(16) unsigned char lds_raw[32768];   // xhi 16KB | xlo 16KB

    const int t  = threadIdx.x;
    const int r0 = blockIdx.x * ROWS_B;
    int rows = rows_total - r0; if (rows > ROWS_B) rows = ROWS_B;

    // ---- stage x: fp32 -> bf16 hi/lo, swizzled LDS [row][k] ----
    {
        const int row = t >> 2;          // 0..63
        const int k0  = (t & 3) << 5;    // 0,32,64,96
        const float4* src = reinterpret_cast<const float4*>(
            s_feats + (size_t)(m_base + r0 + row) * C_F + k0);
        #pragma unroll
        for (int s = 0; s < 4; ++s) {
            float v[8];
            if (row < rows) {
                const float4 a = src[s * 2 + 0];
                const float4 b = src[s * 2 + 1];
                v[0] = a.x; v[1] = a.y; v[2] = a.z; v[3] = a.w;
                v[4] = b.x; v[5] = b.y; v[6] = b.z; v[7] = b.w;
            } else {
                #pragma unroll
                for (int e = 0; e < 8; ++e) v[e] = 0.f;
            }
            short8v hv, lv;
            #pragma unroll
            for (int e = 0; e < 8; ++e) {
                const unsigned short h = bf16_hi(v[e]);
                hv[e] = (short)h;
                lv[e] = (short)bf16_hi(v[e] - bf16_f(h));
            }
            const unsigned addr = (unsigned)((row * 256 + (k0 + s * 8) * 2) ^ ((row & 7) << 4));
            *reinterpret_cast<short8v*>(lds_raw + addr)         = hv;
            *reinterpret_cast<short8v*>(lds_raw + 16384 + addr) = lv;
        }
    }
    __syncthreads();

    const int wave = t >> 6, lane = t & 63;
    const int wc = wave;           // col group 0..3
    const int g  = lane >> 4;      // k-block
    const int ln = lane & 15;

    // ---- phase 1: h = leaky_relu(x @ w1 + b1) ----
    f32x4 acc1[4][2];
    #pragma unroll
    for (int cti = 0; cti < 2; ++cti) {
        const float b = b1[(wc + 4 * cti) * 16 + ln];
        #pragma unroll
        for (int rt = 0; rt < 4; ++rt) acc1[rt][cti] = f32x4{b, b, b, b};
    }
    #pragma unroll
    for (int ks = 0; ks < 4; ++ks) {
        short8v ah[4], al[4];
        #pragma unroll
        for (int rt = 0; rt < 4; ++rt) {
            const int row = rt * 16 + ln;
            const unsigned addr = (unsigned)((row * 256 + (ks * 32 + g * 8) * 2) ^ ((row & 7) << 4));
            ah[rt] = *reinterpret_cast<const short8v*>(lds_raw + addr);
            al[rt] = *reinterpret_cast<const short8v*>(lds_raw + 16384 + addr);
        }
        #pragma unroll
        for (int cti = 0; cti < 2; ++cti) {
            const int col = (wc + 4 * cti) * 16 + ln;
            const size_t off = (size_t)col * C_F + ks * 32 + g * 8;
            const short8v bh = *reinterpret_cast<const short8v*>(w1t_hi + off);
            const short8v bl = *reinterpret_cast<const short8v*>(w1t_lo + off);
            #pragma unroll
            for (int rt = 0; rt < 4; ++rt)
                acc1[rt][cti] = mfma3(ah[rt], al[rt], bh, bl, acc1[rt][cti]);
        }
    }
    __syncthreads();   // all waves done reading x before h overwrites it

    // ---- leaky_relu + bf16 split + writeback (C/D: col=ln, row=g*4+r) ----
    #pragma unroll
    for (int rt = 0; rt < 4; ++rt) {
        #pragma unroll
        for (int cti = 0; cti < 2; ++cti) {
            const int col = (wc + 4 * cti) * 16 + ln;
            #pragma unroll
            for (int r = 0; r < 4; ++r) {
                float v = acc1[rt][cti][r];
                v = v > 0.f ? v : 0.1f * v;
                const int row = rt * 16 + g * 4 + r;
                const unsigned short h = bf16_hi(v);
                const unsigned addr = (unsigned)((row * 256 + col * 2) ^ ((row & 7) << 4));
                *reinterpret_cast<unsigned short*>(lds_raw + addr)         = h;
                *reinterpret_cast<unsigned short*>(lds_raw + 16384 + addr) = bf16_hi(v - bf16_f(h));
            }
        }
    }
    __syncthreads();

    // ---- phase 2: mod = sigmoid(h @ w2) -> global (bf16) ----
    f32x4 acc2[4][4];
    #pragma unroll
    for (int rt = 0; rt < 4; ++rt)
        #pragma unroll
        for (int cs = 0; cs < 4; ++cs) acc2[rt][cs] = f32x4{0.f, 0.f, 0.f, 0.f};

    #pragma unroll
    for (int ks = 0; ks < 4; ++ks) {
        short8v ah[4], al[4];
        #pragma unroll
        for (int rt = 0; rt < 4; ++rt) {
            const int row = rt * 16 + ln;
            const unsigned addr = (unsigned)((row * 256 + (ks * 32 + g * 8) * 2) ^ ((row & 7) << 4));
            ah[rt] = *reinterpret_cast<const short8v*>(lds_raw + addr);
            al[rt] = *reinterpret_cast<const short8v*>(lds_raw + 16384 + addr);
        }
        #pragma unroll
        for (int cs = 0; cs < 4; ++cs) {
            const int ctile = wc + 4 * cs;          // wave-uniform guard, static acc idx
            if (ctile < K_P) {
                const int col = ctile * 16 + ln;
                const size_t off = (size_t)col * C_F + ks * 32 + g * 8;
                const short8v bh = *reinterpret_cast<const short8v*>(w2t_hi + off);
                const short8v bl = *reinterpret_cast<const short8v*>(w2t_lo + off);
                #pragma unroll
                for (int rt = 0; rt < 4; ++rt)
                    acc2[rt][cs] = mfma3(ah[rt], al[rt], bh, bl, acc2[rt][cs]);
            }
        }
    }

    // sigmoid + store (chunk-local row index, bf16)
    #pragma unroll
    for (int rt = 0; rt < 4; ++rt) {
        #pragma unroll
        for (int cs = 0; cs < 4; ++cs) {
            const int ctile = wc + 4 * cs;
            if (ctile < K_P) {
                const int col = ctile * 16 + ln;
                #pragma unroll
                for (int r = 0; r < 4; ++r) {
                    const int row = rt * 16 + g * 4 + r;
                    if (row < rows) {
                        const float v = 1.f / (1.f + __expf(-acc2[rt][cs][r]));
                        modg[(size_t)(r0 + row) * MODC + col] = bf16_hi(v);
                    }
                }
            }
        }
    }
}

// ---------------------------------------------------------------------------
// Kernel 2: geometry + sparse gather/accumulate. One wave (64 lanes) per query
// (round-2-verified structure: 12500 blocks -> latency hidden by TLP).
// ---------------------------------------------------------------------------
__global__ __launch_bounds__(256)
void kpconv_kernel(const float* __restrict__ q_pts,
                   const float* __restrict__ s_pts,
                   const float* __restrict__ s_feats,
                   const int* __restrict__ nbi,
                   const float* __restrict__ da_scale,
                   const float* __restrict__ weights,
                   const float* __restrict__ kp,
                   const unsigned short* __restrict__ mod,  // chunk-local bf16 [rows, 240]
                   float* __restrict__ out,
                   int m_base, int rows_total)
{
    const int t    = threadIdx.x;
    const int lane = t & 63;
    const int r    = blockIdx.x * 4 + (t >> 6);
    if (r >= rows_total) return;
    const int m = m_base + r;

    const float qx = q_pts[m * 3 + 0];
    const float qy = q_pts[m * 3 + 1];
    const float qz = q_pts[m * 3 + 2];
    const float das = da_scale[m];

    int   idx = 0, nn = 0;
    float fl  = 0.f;
    if (lane < H_N) {
        idx = nbi[(size_t)m * H_N + lane];
        const float sx = s_pts[idx * 3 + 0];
        const float sy = s_pts[idx * 3 + 1];
        const float sz = s_pts[idx * 3 + 2];
        // plain fp32 (no fma contraction) to match numpy rounding at argmin ties
        const float dx = __fsub_rn(sx, qx);
        const float dy = __fsub_rn(sy, qy);
        const float dz = __fsub_rn(sz, qz);
        const float dd = __fadd_rn(__fadd_rn(__fmul_rn(dx, dx), __fmul_rn(dy, dy)),
                                   __fmul_rn(dz, dz));
        // |kp| < 1.2 strictly => |d| >= 0.9 + 1.2*da implies infl == 0 exactly.
        const float reach = 0.9f + 1.2f * das;
        if (dd < reach * reach) {
            float best = 3.4e38f; int bi = 0;
            #pragma unroll
            for (int k = 0; k < K_P; ++k) {
                const float ex = __fsub_rn(dx, __fmul_rn(kp[k * 3 + 0], das));
                const float ey = __fsub_rn(dy, __fmul_rn(kp[k * 3 + 1], das));
                const float ez = __fsub_rn(dz, __fmul_rn(kp[k * 3 + 2], das));
                const float d2 = __fadd_rn(__fadd_rn(__fmul_rn(ex, ex), __fmul_rn(ey, ey)),
                                           __fmul_rn(ez, ez));
                if (d2 < best) { best = d2; bi = k; }
            }
            const float f = 1.f - sqrtf(best) / 0.9f;
            fl = fmaxf(f, 0.f);
            nn = bi;
        }
    }

    unsigned long long mask = __ballot(fl > 0.f);
    const int c0 = lane << 1;
    float2 acc = {0.f, 0.f};
    while (mask) {
        const int h = __builtin_ctzll(mask);
        mask &= mask - 1;
        const int   ih = __shfl(idx, h);
        const int   nh = __shfl(nn, h);
        const float fh = __shfl(fl, h);
        const float2 fv = *reinterpret_cast<const float2*>(s_feats + (size_t)ih * C_F + c0);
        const float2 wv = *reinterpret_cast<const float2*>(weights + nh * C_F + c0);
        const float  mv = bf16_f(mod[(size_t)r * MODC + nh * 16 + (lane >> 2)]);
        const float  s  = fh * mv;
        acc.x = fmaf(fv.x * wv.x, s, acc.x);
        acc.y = fmaf(fv.y * wv.y, s, acc.y);
    }
    reinterpret_cast<float2*>(out + (size_t)m * C_F)[lane] = acc;
}

// ---------------------------------------------------------------------------
extern "C" void kernel_launch(void* const* d_in, const int* in_sizes, int n_in,
                              void* d_out, int out_size, void* d_ws, size_t ws_size,
                              hipStream_t stream)
{
    const float* q_pts  = (const float*)d_in[0];
    const float* s_pts  = (const float*)d_in[1];
    const float* s_feat = (const float*)d_in[2];
    const int*   nbi    = (const int*)d_in[3];
    const float* da     = (const float*)d_in[4];
    const float* wts    = (const float*)d_in[5];
    const float* w1     = (const float*)d_in[6];
    const float* b1     = (const float*)d_in[7];
    const float* w2     = (const float*)d_in[8];
    const float* kp     = (const float*)d_in[9];
    float* out = (float*)d_out;

    const int M = in_sizes[4];   // da_scale has M elements

    // workspace layout: split weights (184KB, 256B-aligned) then mod buffer (bf16)
    unsigned short* w1t_hi = (unsigned short*)d_ws;
    unsigned short* w1t_lo = w1t_hi + C_F * C_F;
    unsigned short* w2t_hi = w1t_lo + C_F * C_F;
    unsigned short* w2t_lo = w2t_hi + C_F * MODC;
    size_t woff = ((size_t)(2 * C_F * C_F + 2 * C_F * MODC) * sizeof(unsigned short) + 255) & ~(size_t)255;
    unsigned short* mod = (unsigned short*)((char*)d_ws + woff);

    const int nsplit = (C_F * C_F + C_F * MODC + 255) / 256;
    split_w_kernel<<<dim3(nsplit), 256, 0, stream>>>(w1, w2, w1t_hi, w1t_lo, w2t_hi, w2t_lo);

    // mod needs M*240*2 = 24MB; chunk if workspace is smaller.
    size_t cap = (ws_size - woff) / ((size_t)MODC * sizeof(unsigned short));
    int chunk = (cap >= (size_t)M) ? M : (int)(cap & ~(size_t)63);
    if (chunk < 64) chunk = 64;

    for (int m0 = 0; m0 < M; m0 += chunk) {
        int rows = M - m0; if (rows > chunk) rows = chunk;
        mlp_kernel<<<dim3((rows + ROWS_B - 1) / ROWS_B), 256, 0, stream>>>(
            s_feat, w1t_hi, w1t_lo, w2t_hi, w2t_lo, b1, mod, m0, rows);
        kpconv_kernel<<<dim3((rows + 3) / 4), 256, 0, stream>>>(
            q_pts, s_pts, s_feat, nbi, da, wts, kp, mod, out, m0, rows);
    }
}

// Round 8
// 60.125 us; speedup vs baseline: 1.4928x; 1.1563x over previous
//
#include <hip/hip_runtime.h>
#include <cstddef>
#include <cstdint>

// KPNextBlock: M=N=50000, H=32, C=128, K=15, GROUPS=8, CPG=16 -> K*CPG=240,
// RADIUS=1.2, SIGMA=0.9.
namespace {
constexpr int H_N    = 32;
constexpr int C_F    = 128;
constexpr int K_P    = 15;
constexpr int MODC   = 240;
constexpr int ROWS_B = 64;    // rows per MLP block
}

typedef __attribute__((ext_vector_type(8))) short short8v;
typedef __attribute__((ext_vector_type(4))) float f32x4;

__device__ __forceinline__ unsigned short bf16_hi(float f) {
    unsigned u = __builtin_bit_cast(unsigned, f);
    unsigned r = (u + 0x7FFFu + ((u >> 16) & 1u)) >> 16;
    return (unsigned short)r;
}
__device__ __forceinline__ float bf16_f(unsigned short h) {
    unsigned u = ((unsigned)h) << 16;
    return __builtin_bit_cast(float, u);
}

__device__ __forceinline__ f32x4 mfma3(short8v ah, short8v al, short8v bh, short8v bl, f32x4 c) {
    // (ah+al)*(bh+bl) dropping al*bl: error ~2^-18 relative -> fp32-class.
    c = __builtin_amdgcn_mfma_f32_16x16x32_bf16(ah, bl, c, 0, 0, 0);
    c = __builtin_amdgcn_mfma_f32_16x16x32_bf16(al, bh, c, 0, 0, 0);
    c = __builtin_amdgcn_mfma_f32_16x16x32_bf16(ah, bh, c, 0, 0, 0);
    return c;
}

// ---------------------------------------------------------------------------
// Pre-pass: split w1 [128][128] and w2 [128][240] into bf16 hi/lo, TRANSPOSED
// to [col][k] so MFMA B-fragments are 16B-contiguous per lane.
// ---------------------------------------------------------------------------
__global__ __launch_bounds__(256)
void split_w_kernel(const float* __restrict__ w1, const float* __restrict__ w2,
                    unsigned short* __restrict__ w1t_hi, unsigned short* __restrict__ w1t_lo,
                    unsigned short* __restrict__ w2t_hi, unsigned short* __restrict__ w2t_lo)
{
    const int i = blockIdx.x * 256 + threadIdx.x;
    if (i < C_F * C_F) {
        const int c = i >> 7, j = i & 127;          // w1[c][j]
        const float v = w1[i];
        const unsigned short h = bf16_hi(v);
        w1t_hi[j * C_F + c] = h;
        w1t_lo[j * C_F + c] = bf16_hi(v - bf16_f(h));
    }
    const int i2 = i - C_F * C_F;
    if (i2 >= 0 && i2 < C_F * MODC) {
        const int c = i2 / MODC, j = i2 - c * MODC; // w2[c][j]
        const float v = w2[i2];
        const unsigned short h = bf16_hi(v);
        w2t_hi[j * C_F + c] = h;
        w2t_lo[j * C_F + c] = bf16_hi(v - bf16_f(h));
    }
}

// ---------------------------------------------------------------------------
// Kernel 1: MLP. Per block of 64 rows, 8 waves (512 threads):
//   phase1: wave w owns col-tile w (8 tiles = 128 cols).
//   phase2: wave w owns col-tiles {w, w+8} (15 tiles).
//   stage x (bf16 hi/lo, XOR-swizzled LDS 32KB) -> MFMA p1 (h) -> writeback ->
//   MFMA p2 -> sigmoid -> mod bf16 to global.
// launch_bounds(512,2): VGPR cap 128 (empirical cap = 256/min_waves_per_EU;
// round-4 verified spill-free at this config). 8 waves/block halves the
// per-wave latency chain and doubles waves/CU vs the round-7 grid-starved
// 4-wave config (19% occupancy).
// ---------------------------------------------------------------------------
__global__ __launch_bounds__(512, 2)
void mlp_kernel(const float* __restrict__ s_feats,
                const unsigned short* __restrict__ w1t_hi,
                const unsigned short* __restrict__ w1t_lo,
                const unsigned short* __restrict__ w2t_hi,
                const unsigned short* __restrict__ w2t_lo,
                const float* __restrict__ b1,
                unsigned short* __restrict__ modg,   // bf16 [rows][240]
                int m_base, int rows_total)
{
    __shared__ __align__(16) unsigned char lds_raw[32768];   // xhi 16KB | xlo 16KB

    const int t  = threadIdx.x;
    const int r0 = blockIdx.x * ROWS_B;
    int rows = rows_total - r0; if (rows > ROWS_B) rows = ROWS_B;

    // ---- stage x: fp32 -> bf16 hi/lo, swizzled LDS [row][k] ----
    {
        const int row = t >> 3;          // 0..63 (8 threads/row)
        const int k0  = (t & 7) << 4;    // 0,16,...,112
        const float4* src = reinterpret_cast<const float4*>(
            s_feats + (size_t)(m_base + r0 + row) * C_F + k0);
        #pragma unroll
        for (int s = 0; s < 2; ++s) {
            float v[8];
            if (row < rows) {
                const float4 a = src[s * 2 + 0];
                const float4 b = src[s * 2 + 1];
                v[0] = a.x; v[1] = a.y; v[2] = a.z; v[3] = a.w;
                v[4] = b.x; v[5] = b.y; v[6] = b.z; v[7] = b.w;
            } else {
                #pragma unroll
                for (int e = 0; e < 8; ++e) v[e] = 0.f;
            }
            short8v hv, lv;
            #pragma unroll
            for (int e = 0; e < 8; ++e) {
                const unsigned short h = bf16_hi(v[e]);
                hv[e] = (short)h;
                lv[e] = (short)bf16_hi(v[e] - bf16_f(h));
            }
            const unsigned addr = (unsigned)((row * 256 + (k0 + s * 8) * 2) ^ ((row & 7) << 4));
            *reinterpret_cast<short8v*>(lds_raw + addr)         = hv;
            *reinterpret_cast<short8v*>(lds_raw + 16384 + addr) = lv;
        }
    }
    __syncthreads();

    const int wave = t >> 6, lane = t & 63;
    const int wc = wave;           // col tile 0..7 (phase1)
    const int g  = lane >> 4;      // k-block
    const int ln = lane & 15;

    // ---- phase 1: h = leaky_relu(x @ w1 + b1); wave owns col-tile wc ----
    f32x4 acc1[4];
    {
        const float b = b1[wc * 16 + ln];
        #pragma unroll
        for (int rt = 0; rt < 4; ++rt) acc1[rt] = f32x4{b, b, b, b};
    }
    #pragma unroll
    for (int ks = 0; ks < 4; ++ks) {
        short8v ah[4], al[4];
        #pragma unroll
        for (int rt = 0; rt < 4; ++rt) {
            const int row = rt * 16 + ln;
            const unsigned addr = (unsigned)((row * 256 + (ks * 32 + g * 8) * 2) ^ ((row & 7) << 4));
            ah[rt] = *reinterpret_cast<const short8v*>(lds_raw + addr);
            al[rt] = *reinterpret_cast<const short8v*>(lds_raw + 16384 + addr);
        }
        const int col = wc * 16 + ln;
        const size_t off = (size_t)col * C_F + ks * 32 + g * 8;
        const short8v bh = *reinterpret_cast<const short8v*>(w1t_hi + off);
        const short8v bl = *reinterpret_cast<const short8v*>(w1t_lo + off);
        #pragma unroll
        for (int rt = 0; rt < 4; ++rt)
            acc1[rt] = mfma3(ah[rt], al[rt], bh, bl, acc1[rt]);
    }
    __syncthreads();   // all waves done reading x before h overwrites it

    // ---- leaky_relu + bf16 split + writeback (C/D: col=ln, row=g*4+r) ----
    #pragma unroll
    for (int rt = 0; rt < 4; ++rt) {
        const int col = wc * 16 + ln;
        #pragma unroll
        for (int r = 0; r < 4; ++r) {
            float v = acc1[rt][r];
            v = v > 0.f ? v : 0.1f * v;
            const int row = rt * 16 + g * 4 + r;
            const unsigned short h = bf16_hi(v);
            const unsigned addr = (unsigned)((row * 256 + col * 2) ^ ((row & 7) << 4));
            *reinterpret_cast<unsigned short*>(lds_raw + addr)         = h;
            *reinterpret_cast<unsigned short*>(lds_raw + 16384 + addr) = bf16_hi(v - bf16_f(h));
        }
    }
    __syncthreads();

    // ---- phase 2: mod = sigmoid(h @ w2); wave owns col-tiles {wc, wc+8} ----
    f32x4 acc2[4][2];
    #pragma unroll
    for (int rt = 0; rt < 4; ++rt)
        #pragma unroll
        for (int cs = 0; cs < 2; ++cs) acc2[rt][cs] = f32x4{0.f, 0.f, 0.f, 0.f};

    #pragma unroll
    for (int ks = 0; ks < 4; ++ks) {
        short8v ah[4], al[4];
        #pragma unroll
        for (int rt = 0; rt < 4; ++rt) {
            const int row = rt * 16 + ln;
            const unsigned addr = (unsigned)((row * 256 + (ks * 32 + g * 8) * 2) ^ ((row & 7) << 4));
            ah[rt] = *reinterpret_cast<const short8v*>(lds_raw + addr);
            al[rt] = *reinterpret_cast<const short8v*>(lds_raw + 16384 + addr);
        }
        #pragma unroll
        for (int cs = 0; cs < 2; ++cs) {
            const int ctile = wc + 8 * cs;          // wave-uniform guard, static acc idx
            if (ctile < K_P) {
                const int col = ctile * 16 + ln;
                const size_t off = (size_t)col * C_F + ks * 32 + g * 8;
                const short8v bh = *reinterpret_cast<const short8v*>(w2t_hi + off);
                const short8v bl = *reinterpret_cast<const short8v*>(w2t_lo + off);
                #pragma unroll
                for (int rt = 0; rt < 4; ++rt)
                    acc2[rt][cs] = mfma3(ah[rt], al[rt], bh, bl, acc2[rt][cs]);
            }
        }
    }

    // sigmoid + store (chunk-local row index, bf16)
    #pragma unroll
    for (int rt = 0; rt < 4; ++rt) {
        #pragma unroll
        for (int cs = 0; cs < 2; ++cs) {
            const int ctile = wc + 8 * cs;
            if (ctile < K_P) {
                const int col = ctile * 16 + ln;
                #pragma unroll
                for (int r = 0; r < 4; ++r) {
                    const int row = rt * 16 + g * 4 + r;
                    if (row < rows) {
                        const float v = 1.f / (1.f + __expf(-acc2[rt][cs][r]));
                        modg[(size_t)(r0 + row) * MODC + col] = bf16_hi(v);
                    }
                }
            }
        }
    }
}

// ---------------------------------------------------------------------------
// Kernel 2: geometry + sparse gather/accumulate. One wave (64 lanes) per query
// (round-2-verified structure: 12500 blocks -> latency hidden by TLP).
// ---------------------------------------------------------------------------
__global__ __launch_bounds__(256)
void kpconv_kernel(const float* __restrict__ q_pts,
                   const float* __restrict__ s_pts,
                   const float* __restrict__ s_feats,
                   const int* __restrict__ nbi,
                   const float* __restrict__ da_scale,
                   const float* __restrict__ weights,
                   const float* __restrict__ kp,
                   const unsigned short* __restrict__ mod,  // chunk-local bf16 [rows, 240]
                   float* __restrict__ out,
                   int m_base, int rows_total)
{
    const int t    = threadIdx.x;
    const int lane = t & 63;
    const int r    = blockIdx.x * 4 + (t >> 6);
    if (r >= rows_total) return;
    const int m = m_base + r;

    const float qx = q_pts[m * 3 + 0];
    const float qy = q_pts[m * 3 + 1];
    const float qz = q_pts[m * 3 + 2];
    const float das = da_scale[m];

    int   idx = 0, nn = 0;
    float fl  = 0.f;
    if (lane < H_N) {
        idx = nbi[(size_t)m * H_N + lane];
        const float sx = s_pts[idx * 3 + 0];
        const float sy = s_pts[idx * 3 + 1];
        const float sz = s_pts[idx * 3 + 2];
        // plain fp32 (no fma contraction) to match numpy rounding at argmin ties
        const float dx = __fsub_rn(sx, qx);
        const float dy = __fsub_rn(sy, qy);
        const float dz = __fsub_rn(sz, qz);
        const float dd = __fadd_rn(__fadd_rn(__fmul_rn(dx, dx), __fmul_rn(dy, dy)),
                                   __fmul_rn(dz, dz));
        // |kp| < 1.2 strictly => |d| >= 0.9 + 1.2*da implies infl == 0 exactly.
        const float reach = 0.9f + 1.2f * das;
        if (dd < reach * reach) {
            float best = 3.4e38f; int bi = 0;
            #pragma unroll
            for (int k = 0; k < K_P; ++k) {
                const float ex = __fsub_rn(dx, __fmul_rn(kp[k * 3 + 0], das));
                const float ey = __fsub_rn(dy, __fmul_rn(kp[k * 3 + 1], das));
                const float ez = __fsub_rn(dz, __fmul_rn(kp[k * 3 + 2], das));
                const float d2 = __fadd_rn(__fadd_rn(__fmul_rn(ex, ex), __fmul_rn(ey, ey)),
                                           __fmul_rn(ez, ez));
                if (d2 < best) { best = d2; bi = k; }
            }
            const float f = 1.f - sqrtf(best) / 0.9f;
            fl = fmaxf(f, 0.f);
            nn = bi;
        }
    }

    unsigned long long mask = __ballot(fl > 0.f);
    const int c0 = lane << 1;
    float2 acc = {0.f, 0.f};
    while (mask) {
        const int h = __builtin_ctzll(mask);
        mask &= mask - 1;
        const int   ih = __shfl(idx, h);
        const int   nh = __shfl(nn, h);
        const float fh = __shfl(fl, h);
        const float2 fv = *reinterpret_cast<const float2*>(s_feats + (size_t)ih * C_F + c0);
        const float2 wv = *reinterpret_cast<const float2*>(weights + nh * C_F + c0);
        const float  mv = bf16_f(mod[(size_t)r * MODC + nh * 16 + (lane >> 2)]);
        const float  s  = fh * mv;
        acc.x = fmaf(fv.x * wv.x, s, acc.x);
        acc.y = fmaf(fv.y * wv.y, s, acc.y);
    }
    reinterpret_cast<float2*>(out + (size_t)m * C_F)[lane] = acc;
}

// ---------------------------------------------------------------------------
extern "C" void kernel_launch(void* const* d_in, const int* in_sizes, int n_in,
                              void* d_out, int out_size, void* d_ws, size_t ws_size,
                              hipStream_t stream)
{
    const float* q_pts  = (const float*)d_in[0];
    const float* s_pts  = (const float*)d_in[1];
    const float* s_feat = (const float*)d_in[2];
    const int*   nbi    = (const int*)d_in[3];
    const float* da     = (const float*)d_in[4];
    const float* wts    = (const float*)d_in[5];
    const float* w1     = (const float*)d_in[6];
    const float* b1     = (const float*)d_in[7];
    const float* w2     = (const float*)d_in[8];
    const float* kp     = (const float*)d_in[9];
    float* out = (float*)d_out;

    const int M = in_sizes[4];   // da_scale has M elements

    // workspace layout: split weights (184KB, 256B-aligned) then mod buffer (bf16)
    unsigned short* w1t_hi = (unsigned short*)d_ws;
    unsigned short* w1t_lo = w1t_hi + C_F * C_F;
    unsigned short* w2t_hi = w1t_lo + C_F * C_F;
    unsigned short* w2t_lo = w2t_hi + C_F * MODC;
    size_t woff = ((size_t)(2 * C_F * C_F + 2 * C_F * MODC) * sizeof(unsigned short) + 255) & ~(size_t)255;
    unsigned short* mod = (unsigned short*)((char*)d_ws + woff);

    const int nsplit = (C_F * C_F + C_F * MODC + 255) / 256;
    split_w_kernel<<<dim3(nsplit), 256, 0, stream>>>(w1, w2, w1t_hi, w1t_lo, w2t_hi, w2t_lo);

    // mod needs M*240*2 = 24MB; chunk if workspace is smaller.
    size_t cap = (ws_size - woff) / ((size_t)MODC * sizeof(unsigned short));
    int chunk = (cap >= (size_t)M) ? M : (int)(cap & ~(size_t)63);
    if (chunk < 64) chunk = 64;

    for (int m0 = 0; m0 < M; m0 += chunk) {
        int rows = M - m0; if (rows > chunk) rows = chunk;
        mlp_kernel<<<dim3((rows + ROWS_B - 1) / ROWS_B), 512, 0, stream>>>(
            s_feat, w1t_hi, w1t_lo, w2t_hi, w2t_lo, b1, mod, m0, rows);
        kpconv_kernel<<<dim3((rows + 3) / 4), 256, 0, stream>>>(
            q_pts, s_pts, s_feat, nbi, da, wts, kp, mod, out, m0, rows);
    }
}

// Round 9
// 53.291 us; speedup vs baseline: 1.6842x; 1.1282x over previous
//
#include <hip/hip_runtime.h>
#include <cstddef>
#include <cstdint>

// KPNextBlock: M=N=50000, H=32, C=128, K=15, GROUPS=8, CPG=16 -> K*CPG=240,
// RADIUS=1.2, SIGMA=0.9.
namespace {
constexpr int H_N    = 32;
constexpr int C_F    = 128;
constexpr int K_P    = 15;
constexpr int MODC   = 240;
constexpr int ROWS_B = 64;    // rows per MLP chunk
// LDS layout (bytes): w1t swz 32KB | w2t swz 60KB | x/h swz 16KB = 108KB
constexpr int W1_OFF = 0;
constexpr int W2_OFF = 32768;
constexpr int X_OFF  = 94208;
constexpr int LDS_SZ = 110592;
}

typedef __attribute__((ext_vector_type(8))) short short8v;
typedef __attribute__((ext_vector_type(4))) float f32x4;

__device__ __forceinline__ unsigned short bf16_hi(float f) {
    unsigned u = __builtin_bit_cast(unsigned, f);
    unsigned r = (u + 0x7FFFu + ((u >> 16) & 1u)) >> 16;
    return (unsigned short)r;
}
__device__ __forceinline__ float bf16_f(unsigned short h) {
    unsigned u = ((unsigned)h) << 16;
    return __builtin_bit_cast(float, u);
}

// ---------------------------------------------------------------------------
// Pre-pass: w1 [128][128] and w2 [128][240] -> single bf16, TRANSPOSED to
// [col][k] so MFMA B-fragments are 16B-contiguous per lane.
// ---------------------------------------------------------------------------
__global__ __launch_bounds__(256)
void split_w_kernel(const float* __restrict__ w1, const float* __restrict__ w2,
                    unsigned short* __restrict__ w1t, unsigned short* __restrict__ w2t)
{
    const int i = blockIdx.x * 256 + threadIdx.x;
    if (i < C_F * C_F) {
        const int c = i >> 7, j = i & 127;          // w1[c][j]
        w1t[j * C_F + c] = bf16_hi(w1[i]);
    }
    const int i2 = i - C_F * C_F;
    if (i2 >= 0 && i2 < C_F * MODC) {
        const int c = i2 / MODC, j = i2 - c * MODC; // w2[c][j]
        w2t[j * C_F + c] = bf16_hi(w2[i2]);
    }
}

// ---------------------------------------------------------------------------
// Kernel 1: persistent MLP, weights LDS-resident.
// 256 blocks (1/CU, LDS 108KB), 512 threads (8 waves). Per block:
//   stage w1t+w2t into swizzled LDS ONCE, then loop over 64-row chunks:
//   stage x (bf16, swizzled) -> MFMA p1 (wave w owns col-tile w) ->
//   leaky_relu writeback (h over x) -> MFMA p2 (tiles {w, w+8}) ->
//   sigmoid -> mod bf16 to global.
// All compute-loop loads are LDS -> no L2/HBM latency on the critical path.
// ---------------------------------------------------------------------------
__global__ __launch_bounds__(512, 2)
void mlp_kernel(const float* __restrict__ s_feats,
                const unsigned short* __restrict__ w1t,
                const unsigned short* __restrict__ w2t,
                const float* __restrict__ b1,
                unsigned short* __restrict__ modg,   // bf16 [rows][240]
                int m_base, int rows_total)
{
    __shared__ __align__(16) unsigned char lds[LDS_SZ];

    const int t = threadIdx.x;

    // ---- stage weights into swizzled LDS (once per block) ----
    for (int gi = t; gi < 2048; gi += 512) {              // w1t: 2048 x 16B
        const int col = gi >> 4, k8 = gi & 15;
        const short8v v = *reinterpret_cast<const short8v*>(w1t + gi * 8);
        const unsigned addr = (unsigned)((col * 256 + k8 * 16) ^ ((col & 7) << 4));
        *reinterpret_cast<short8v*>(lds + W1_OFF + addr) = v;
    }
    for (int gi = t; gi < 3840; gi += 512) {              // w2t: 3840 x 16B
        const int col = gi >> 4, k8 = gi & 15;
        const short8v v = *reinterpret_cast<const short8v*>(w2t + gi * 8);
        const unsigned addr = (unsigned)((col * 256 + k8 * 16) ^ ((col & 7) << 4));
        *reinterpret_cast<short8v*>(lds + W2_OFF + addr) = v;
    }

    const int wave = t >> 6, lane = t & 63;
    const int wc = wave;           // col tile 0..7
    const int g  = lane >> 4;      // k-block
    const int ln = lane & 15;
    const float bias = b1[wc * 16 + ln];

    const int nchunks = (rows_total + ROWS_B - 1) / ROWS_B;
    for (int ch = blockIdx.x; ch < nchunks; ch += gridDim.x) {
        const int r0 = ch * ROWS_B;
        const int rows = min(rows_total - r0, ROWS_B);

        __syncthreads();   // weights staged (first iter) / prev chunk p2 reads done

        // ---- stage x chunk: fp32 -> bf16, swizzled LDS [row][k] ----
        {
            const int row = t >> 3;          // 0..63
            const int k0  = (t & 7) << 4;    // 0,16,...,112
            const float4* src = reinterpret_cast<const float4*>(
                s_feats + (size_t)(m_base + r0 + row) * C_F + k0);
            #pragma unroll
            for (int s = 0; s < 2; ++s) {
                float v[8];
                if (row < rows) {
                    const float4 a = src[s * 2 + 0];
                    const float4 b = src[s * 2 + 1];
                    v[0] = a.x; v[1] = a.y; v[2] = a.z; v[3] = a.w;
                    v[4] = b.x; v[5] = b.y; v[6] = b.z; v[7] = b.w;
                } else {
                    #pragma unroll
                    for (int e = 0; e < 8; ++e) v[e] = 0.f;
                }
                short8v hv;
                #pragma unroll
                for (int e = 0; e < 8; ++e) hv[e] = (short)bf16_hi(v[e]);
                const unsigned addr = (unsigned)((row * 256 + (k0 + s * 8) * 2) ^ ((row & 7) << 4));
                *reinterpret_cast<short8v*>(lds + X_OFF + addr) = hv;
            }
        }
        __syncthreads();

        // ---- phase 1: h = leaky_relu(x @ w1 + b1); wave owns col-tile wc ----
        f32x4 acc1[4];
        #pragma unroll
        for (int rt = 0; rt < 4; ++rt) acc1[rt] = f32x4{bias, bias, bias, bias};

        #pragma unroll
        for (int ks = 0; ks < 4; ++ks) {
            short8v a[4];
            #pragma unroll
            for (int rt = 0; rt < 4; ++rt) {
                const int row = rt * 16 + ln;
                const unsigned addr = (unsigned)((row * 256 + (ks * 32 + g * 8) * 2) ^ ((row & 7) << 4));
                a[rt] = *reinterpret_cast<const short8v*>(lds + X_OFF + addr);
            }
            const int col = wc * 16 + ln;
            const unsigned baddr = (unsigned)((col * 256 + (ks * 32 + g * 8) * 2) ^ ((col & 7) << 4));
            const short8v b = *reinterpret_cast<const short8v*>(lds + W1_OFF + baddr);
            #pragma unroll
            for (int rt = 0; rt < 4; ++rt)
                acc1[rt] = __builtin_amdgcn_mfma_f32_16x16x32_bf16(a[rt], b, acc1[rt], 0, 0, 0);
        }
        __syncthreads();   // all waves done reading x before h overwrites it

        // ---- leaky_relu + writeback (C/D: col=ln, row=g*4+r) ----
        #pragma unroll
        for (int rt = 0; rt < 4; ++rt) {
            const int col = wc * 16 + ln;
            #pragma unroll
            for (int r = 0; r < 4; ++r) {
                float v = acc1[rt][r];
                v = v > 0.f ? v : 0.1f * v;
                const int row = rt * 16 + g * 4 + r;
                const unsigned addr = (unsigned)((row * 256 + col * 2) ^ ((row & 7) << 4));
                *reinterpret_cast<unsigned short*>(lds + X_OFF + addr) = bf16_hi(v);
            }
        }
        __syncthreads();

        // ---- phase 2: mod = sigmoid(h @ w2); wave owns tiles {wc, wc+8} ----
        f32x4 acc2[4][2];
        #pragma unroll
        for (int rt = 0; rt < 4; ++rt)
            #pragma unroll
            for (int cs = 0; cs < 2; ++cs) acc2[rt][cs] = f32x4{0.f, 0.f, 0.f, 0.f};

        #pragma unroll
        for (int ks = 0; ks < 4; ++ks) {
            short8v a[4];
            #pragma unroll
            for (int rt = 0; rt < 4; ++rt) {
                const int row = rt * 16 + ln;
                const unsigned addr = (unsigned)((row * 256 + (ks * 32 + g * 8) * 2) ^ ((row & 7) << 4));
                a[rt] = *reinterpret_cast<const short8v*>(lds + X_OFF + addr);
            }
            #pragma unroll
            for (int cs = 0; cs < 2; ++cs) {
                const int ctile = wc + 8 * cs;          // wave-uniform guard, static acc idx
                if (ctile < K_P) {
                    const int col = ctile * 16 + ln;
                    const unsigned baddr = (unsigned)((col * 256 + (ks * 32 + g * 8) * 2) ^ ((col & 7) << 4));
                    const short8v b = *reinterpret_cast<const short8v*>(lds + W2_OFF + baddr);
                    #pragma unroll
                    for (int rt = 0; rt < 4; ++rt)
                        acc2[rt][cs] = __builtin_amdgcn_mfma_f32_16x16x32_bf16(a[rt], b, acc2[rt][cs], 0, 0, 0);
                }
            }
        }

        // ---- sigmoid + store (bf16) ----
        #pragma unroll
        for (int rt = 0; rt < 4; ++rt) {
            #pragma unroll
            for (int cs = 0; cs < 2; ++cs) {
                const int ctile = wc + 8 * cs;
                if (ctile < K_P) {
                    const int col = ctile * 16 + ln;
                    #pragma unroll
                    for (int r = 0; r < 4; ++r) {
                        const int row = rt * 16 + g * 4 + r;
                        if (row < rows) {
                            const float v = 1.f / (1.f + __expf(-acc2[rt][cs][r]));
                            modg[(size_t)(r0 + row) * MODC + col] = bf16_hi(v);
                        }
                    }
                }
            }
        }
    }
}

// ---------------------------------------------------------------------------
// Kernel 2: geometry + sparse gather/accumulate. One wave (64 lanes) per query
// (round-2-verified structure: 12500 blocks -> latency hidden by TLP).
// ---------------------------------------------------------------------------
__global__ __launch_bounds__(256)
void kpconv_kernel(const float* __restrict__ q_pts,
                   const float* __restrict__ s_pts,
                   const float* __restrict__ s_feats,
                   const int* __restrict__ nbi,
                   const float* __restrict__ da_scale,
                   const float* __restrict__ weights,
                   const float* __restrict__ kp,
                   const unsigned short* __restrict__ mod,  // chunk-local bf16 [rows, 240]
                   float* __restrict__ out,
                   int m_base, int rows_total)
{
    const int t    = threadIdx.x;
    const int lane = t & 63;
    const int r    = blockIdx.x * 4 + (t >> 6);
    if (r >= rows_total) return;
    const int m = m_base + r;

    const float qx = q_pts[m * 3 + 0];
    const float qy = q_pts[m * 3 + 1];
    const float qz = q_pts[m * 3 + 2];
    const float das = da_scale[m];

    int   idx = 0, nn = 0;
    float fl  = 0.f;
    if (lane < H_N) {
        idx = nbi[(size_t)m * H_N + lane];
        const float sx = s_pts[idx * 3 + 0];
        const float sy = s_pts[idx * 3 + 1];
        const float sz = s_pts[idx * 3 + 2];
        // plain fp32 (no fma contraction) to match numpy rounding at argmin ties
        const float dx = __fsub_rn(sx, qx);
        const float dy = __fsub_rn(sy, qy);
        const float dz = __fsub_rn(sz, qz);
        const float dd = __fadd_rn(__fadd_rn(__fmul_rn(dx, dx), __fmul_rn(dy, dy)),
                                   __fmul_rn(dz, dz));
        // |kp| < 1.2 strictly => |d| >= 0.9 + 1.2*da implies infl == 0 exactly.
        const float reach = 0.9f + 1.2f * das;
        if (dd < reach * reach) {
            float best = 3.4e38f; int bi = 0;
            #pragma unroll
            for (int k = 0; k < K_P; ++k) {
                const float ex = __fsub_rn(dx, __fmul_rn(kp[k * 3 + 0], das));
                const float ey = __fsub_rn(dy, __fmul_rn(kp[k * 3 + 1], das));
                const float ez = __fsub_rn(dz, __fmul_rn(kp[k * 3 + 2], das));
                const float d2 = __fadd_rn(__fadd_rn(__fmul_rn(ex, ex), __fmul_rn(ey, ey)),
                                           __fmul_rn(ez, ez));
                if (d2 < best) { best = d2; bi = k; }
            }
            const float f = 1.f - sqrtf(best) / 0.9f;
            fl = fmaxf(f, 0.f);
            nn = bi;
        }
    }

    unsigned long long mask = __ballot(fl > 0.f);
    const int c0 = lane << 1;
    float2 acc = {0.f, 0.f};
    while (mask) {
        const int h = __builtin_ctzll(mask);
        mask &= mask - 1;
        const int   ih = __shfl(idx, h);
        const int   nh = __shfl(nn, h);
        const float fh = __shfl(fl, h);
        const float2 fv = *reinterpret_cast<const float2*>(s_feats + (size_t)ih * C_F + c0);
        const float2 wv = *reinterpret_cast<const float2*>(weights + nh * C_F + c0);
        const float  mv = bf16_f(mod[(size_t)r * MODC + nh * 16 + (lane >> 2)]);
        const float  s  = fh * mv;
        acc.x = fmaf(fv.x * wv.x, s, acc.x);
        acc.y = fmaf(fv.y * wv.y, s, acc.y);
    }
    reinterpret_cast<float2*>(out + (size_t)m * C_F)[lane] = acc;
}

// ---------------------------------------------------------------------------
extern "C" void kernel_launch(void* const* d_in, const int* in_sizes, int n_in,
                              void* d_out, int out_size, void* d_ws, size_t ws_size,
                              hipStream_t stream)
{
    const float* q_pts  = (const float*)d_in[0];
    const float* s_pts  = (const float*)d_in[1];
    const float* s_feat = (const float*)d_in[2];
    const int*   nbi    = (const int*)d_in[3];
    const float* da     = (const float*)d_in[4];
    const float* wts    = (const float*)d_in[5];
    const float* w1     = (const float*)d_in[6];
    const float* b1     = (const float*)d_in[7];
    const float* w2     = (const float*)d_in[8];
    const float* kp     = (const float*)d_in[9];
    float* out = (float*)d_out;

    const int M = in_sizes[4];   // da_scale has M elements

    // workspace layout: bf16 transposed weights (92KB, 256B-aligned) then mod (bf16)
    unsigned short* w1t = (unsigned short*)d_ws;
    unsigned short* w2t = w1t + C_F * C_F;
    size_t woff = ((size_t)(C_F * C_F + C_F * MODC) * sizeof(unsigned short) + 255) & ~(size_t)255;
    unsigned short* mod = (unsigned short*)((char*)d_ws + woff);

    const int nsplit = (C_F * C_F + C_F * MODC + 255) / 256;
    split_w_kernel<<<dim3(nsplit), 256, 0, stream>>>(w1, w2, w1t, w2t);

    // mod needs M*240*2 = 24MB; chunk if workspace is smaller.
    size_t cap = (ws_size - woff) / ((size_t)MODC * sizeof(unsigned short));
    int chunk = (cap >= (size_t)M) ? M : (int)(cap & ~(size_t)63);
    if (chunk < 64) chunk = 64;

    for (int m0 = 0; m0 < M; m0 += chunk) {
        int rows = M - m0; if (rows > chunk) rows = chunk;
        const int nchunks = (rows + ROWS_B - 1) / ROWS_B;
        const int grid = nchunks < 256 ? nchunks : 256;
        mlp_kernel<<<dim3(grid), 512, 0, stream>>>(
            s_feat, w1t, w2t, b1, mod, m0, rows);
        kpconv_kernel<<<dim3((rows + 3) / 4), 256, 0, stream>>>(
            q_pts, s_pts, s_feat, nbi, da, wts, kp, mod, out, m0, rows);
    }
}

// Round 10
// 52.009 us; speedup vs baseline: 1.7258x; 1.0247x over previous
//
#include <hip/hip_runtime.h>
#include <cstddef>
#include <cstdint>

// KPNextBlock: M=N=50000, H=32, C=128, K=15, GROUPS=8, CPG=16 -> K*CPG=240,
// RADIUS=1.2, SIGMA=0.9.
namespace {
constexpr int H_N    = 32;
constexpr int C_F    = 128;
constexpr int K_P    = 15;
constexpr int MODC   = 240;
constexpr int ROWS_B = 64;    // rows per MLP chunk
// LDS layout (bytes): w1t swz 32KB | w2t swz 60KB | x/h swz 16KB | mod 30KB
constexpr int W1_OFF  = 0;
constexpr int W2_OFF  = 32768;
constexpr int X_OFF   = 94208;
constexpr int MOD_OFF = 110592;
constexpr int LDS_SZ  = 141312;   // 138 KB -> 1 block/CU
}

typedef __attribute__((ext_vector_type(8))) short short8v;
typedef __attribute__((ext_vector_type(4))) float f32x4;

__device__ __forceinline__ unsigned short bf16_hi(float f) {
    unsigned u = __builtin_bit_cast(unsigned, f);
    unsigned r = (u + 0x7FFFu + ((u >> 16) & 1u)) >> 16;
    return (unsigned short)r;
}
__device__ __forceinline__ float bf16_f(unsigned short h) {
    unsigned u = ((unsigned)h) << 16;
    return __builtin_bit_cast(float, u);
}

// ---------------------------------------------------------------------------
// Pre-pass: w1 [128][128] and w2 [128][240] -> single bf16, TRANSPOSED to
// [col][k] so MFMA B-fragments are 16B-contiguous per lane.
// ---------------------------------------------------------------------------
__global__ __launch_bounds__(256)
void split_w_kernel(const float* __restrict__ w1, const float* __restrict__ w2,
                    unsigned short* __restrict__ w1t, unsigned short* __restrict__ w2t)
{
    const int i = blockIdx.x * 256 + threadIdx.x;
    if (i < C_F * C_F) {
        const int c = i >> 7, j = i & 127;          // w1[c][j]
        w1t[j * C_F + c] = bf16_hi(w1[i]);
    }
    const int i2 = i - C_F * C_F;
    if (i2 >= 0 && i2 < C_F * MODC) {
        const int c = i2 / MODC, j = i2 - c * MODC; // w2[c][j]
        w2t[j * C_F + c] = bf16_hi(w2[i2]);
    }
}

// ---------------------------------------------------------------------------
// Kernel 1: persistent MLP, weights LDS-resident.
// 256 blocks (1/CU, LDS 138KB), 512 threads (8 waves). Per block:
//   stage w1t+w2t into swizzled LDS ONCE, then loop over 64-row chunks:
//   stage x (bf16, swizzled) -> MFMA p1 -> leaky_relu writeback ->
//   MFMA p2 -> sigmoid -> mod tile in LDS -> COALESCED copy-out (short8v).
// The LDS mod staging replaces ~15360 scalar 2B global stores per chunk with
// 1920 16B stores (8x fewer VMEM instructions -- round-9's hidden ~20us).
// ---------------------------------------------------------------------------
__global__ __launch_bounds__(512, 2)
void mlp_kernel(const float* __restrict__ s_feats,
                const unsigned short* __restrict__ w1t,
                const unsigned short* __restrict__ w2t,
                const float* __restrict__ b1,
                unsigned short* __restrict__ modg,   // bf16 [rows][240]
                int m_base, int rows_total)
{
    __shared__ __align__(16) unsigned char lds[LDS_SZ];

    const int t = threadIdx.x;

    // ---- stage weights into swizzled LDS (once per block) ----
    for (int gi = t; gi < 2048; gi += 512) {              // w1t: 2048 x 16B
        const int col = gi >> 4, k8 = gi & 15;
        const short8v v = *reinterpret_cast<const short8v*>(w1t + gi * 8);
        const unsigned addr = (unsigned)((col * 256 + k8 * 16) ^ ((col & 7) << 4));
        *reinterpret_cast<short8v*>(lds + W1_OFF + addr) = v;
    }
    for (int gi = t; gi < 3840; gi += 512) {              // w2t: 3840 x 16B
        const int col = gi >> 4, k8 = gi & 15;
        const short8v v = *reinterpret_cast<const short8v*>(w2t + gi * 8);
        const unsigned addr = (unsigned)((col * 256 + k8 * 16) ^ ((col & 7) << 4));
        *reinterpret_cast<short8v*>(lds + W2_OFF + addr) = v;
    }

    const int wave = t >> 6, lane = t & 63;
    const int wc = wave;           // col tile 0..7
    const int g  = lane >> 4;      // k-block
    const int ln = lane & 15;
    const float bias = b1[wc * 16 + ln];

    const int nchunks = (rows_total + ROWS_B - 1) / ROWS_B;
    for (int ch = blockIdx.x; ch < nchunks; ch += gridDim.x) {
        const int r0 = ch * ROWS_B;
        const int rows = min(rows_total - r0, ROWS_B);

        __syncthreads();   // weights staged (first iter) / prev copy-out done

        // ---- stage x chunk: fp32 -> bf16, swizzled LDS [row][k] ----
        {
            const int row = t >> 3;          // 0..63
            const int k0  = (t & 7) << 4;    // 0,16,...,112
            const float4* src = reinterpret_cast<const float4*>(
                s_feats + (size_t)(m_base + r0 + row) * C_F + k0);
            #pragma unroll
            for (int s = 0; s < 2; ++s) {
                float v[8];
                if (row < rows) {
                    const float4 a = src[s * 2 + 0];
                    const float4 b = src[s * 2 + 1];
                    v[0] = a.x; v[1] = a.y; v[2] = a.z; v[3] = a.w;
                    v[4] = b.x; v[5] = b.y; v[6] = b.z; v[7] = b.w;
                } else {
                    #pragma unroll
                    for (int e = 0; e < 8; ++e) v[e] = 0.f;
                }
                short8v hv;
                #pragma unroll
                for (int e = 0; e < 8; ++e) hv[e] = (short)bf16_hi(v[e]);
                const unsigned addr = (unsigned)((row * 256 + (k0 + s * 8) * 2) ^ ((row & 7) << 4));
                *reinterpret_cast<short8v*>(lds + X_OFF + addr) = hv;
            }
        }
        __syncthreads();

        // ---- phase 1: h = leaky_relu(x @ w1 + b1); wave owns col-tile wc ----
        f32x4 acc1[4];
        #pragma unroll
        for (int rt = 0; rt < 4; ++rt) acc1[rt] = f32x4{bias, bias, bias, bias};

        #pragma unroll
        for (int ks = 0; ks < 4; ++ks) {
            short8v a[4];
            #pragma unroll
            for (int rt = 0; rt < 4; ++rt) {
                const int row = rt * 16 + ln;
                const unsigned addr = (unsigned)((row * 256 + (ks * 32 + g * 8) * 2) ^ ((row & 7) << 4));
                a[rt] = *reinterpret_cast<const short8v*>(lds + X_OFF + addr);
            }
            const int col = wc * 16 + ln;
            const unsigned baddr = (unsigned)((col * 256 + (ks * 32 + g * 8) * 2) ^ ((col & 7) << 4));
            const short8v b = *reinterpret_cast<const short8v*>(lds + W1_OFF + baddr);
            #pragma unroll
            for (int rt = 0; rt < 4; ++rt)
                acc1[rt] = __builtin_amdgcn_mfma_f32_16x16x32_bf16(a[rt], b, acc1[rt], 0, 0, 0);
        }
        __syncthreads();   // all waves done reading x before h overwrites it

        // ---- leaky_relu + writeback (C/D: col=ln, row=g*4+r) ----
        #pragma unroll
        for (int rt = 0; rt < 4; ++rt) {
            const int col = wc * 16 + ln;
            #pragma unroll
            for (int r = 0; r < 4; ++r) {
                float v = acc1[rt][r];
                v = v > 0.f ? v : 0.1f * v;
                const int row = rt * 16 + g * 4 + r;
                const unsigned addr = (unsigned)((row * 256 + col * 2) ^ ((row & 7) << 4));
                *reinterpret_cast<unsigned short*>(lds + X_OFF + addr) = bf16_hi(v);
            }
        }
        __syncthreads();

        // ---- phase 2: mod = sigmoid(h @ w2); wave owns tiles {wc, wc+8} ----
        f32x4 acc2[4][2];
        #pragma unroll
        for (int rt = 0; rt < 4; ++rt)
            #pragma unroll
            for (int cs = 0; cs < 2; ++cs) acc2[rt][cs] = f32x4{0.f, 0.f, 0.f, 0.f};

        #pragma unroll
        for (int ks = 0; ks < 4; ++ks) {
            short8v a[4];
            #pragma unroll
            for (int rt = 0; rt < 4; ++rt) {
                const int row = rt * 16 + ln;
                const unsigned addr = (unsigned)((row * 256 + (ks * 32 + g * 8) * 2) ^ ((row & 7) << 4));
                a[rt] = *reinterpret_cast<const short8v*>(lds + X_OFF + addr);
            }
            #pragma unroll
            for (int cs = 0; cs < 2; ++cs) {
                const int ctile = wc + 8 * cs;          // wave-uniform guard, static acc idx
                if (ctile < K_P) {
                    const int col = ctile * 16 + ln;
                    const unsigned baddr = (unsigned)((col * 256 + (ks * 32 + g * 8) * 2) ^ ((col & 7) << 4));
                    const short8v b = *reinterpret_cast<const short8v*>(lds + W2_OFF + baddr);
                    #pragma unroll
                    for (int rt = 0; rt < 4; ++rt)
                        acc2[rt][cs] = __builtin_amdgcn_mfma_f32_16x16x32_bf16(a[rt], b, acc2[rt][cs], 0, 0, 0);
                }
            }
        }

        // ---- sigmoid -> mod tile in LDS (bf16, linear [64][240]) ----
        #pragma unroll
        for (int rt = 0; rt < 4; ++rt) {
            #pragma unroll
            for (int cs = 0; cs < 2; ++cs) {
                const int ctile = wc + 8 * cs;
                if (ctile < K_P) {
                    const int col = ctile * 16 + ln;
                    #pragma unroll
                    for (int r = 0; r < 4; ++r) {
                        const int row = rt * 16 + g * 4 + r;
                        const float v = 1.f / (1.f + __expf(-acc2[rt][cs][r]));
                        *reinterpret_cast<unsigned short*>(lds + MOD_OFF + row * 480 + col * 2) = bf16_hi(v);
                    }
                }
            }
        }
        __syncthreads();

        // ---- coalesced copy-out: rows*30 x 16B ----
        for (int gi = t; gi < rows * 30; gi += 512) {
            const int row = gi / 30, u = gi - row * 30;
            const short8v v = *reinterpret_cast<const short8v*>(lds + MOD_OFF + row * 480 + u * 16);
            *reinterpret_cast<short8v*>(modg + (size_t)(r0 + row) * MODC + u * 8) = v;
        }
    }
}

// ---------------------------------------------------------------------------
// Kernel 2: geometry + sparse gather/accumulate. One wave (64 lanes) per query
// (round-2-verified structure: 12500 blocks -> latency hidden by TLP).
// ---------------------------------------------------------------------------
__global__ __launch_bounds__(256)
void kpconv_kernel(const float* __restrict__ q_pts,
                   const float* __restrict__ s_pts,
                   const float* __restrict__ s_feats,
                   const int* __restrict__ nbi,
                   const float* __restrict__ da_scale,
                   const float* __restrict__ weights,
                   const float* __restrict__ kp,
                   const unsigned short* __restrict__ mod,  // chunk-local bf16 [rows, 240]
                   float* __restrict__ out,
                   int m_base, int rows_total)
{
    const int t    = threadIdx.x;
    const int lane = t & 63;
    const int r    = blockIdx.x * 4 + (t >> 6);
    if (r >= rows_total) return;
    const int m = m_base + r;

    const float qx = q_pts[m * 3 + 0];
    const float qy = q_pts[m * 3 + 1];
    const float qz = q_pts[m * 3 + 2];
    const float das = da_scale[m];

    int   idx = 0, nn = 0;
    float fl  = 0.f;
    if (lane < H_N) {
        idx = nbi[(size_t)m * H_N + lane];
        const float sx = s_pts[idx * 3 + 0];
        const float sy = s_pts[idx * 3 + 1];
        const float sz = s_pts[idx * 3 + 2];
        // plain fp32 (no fma contraction) to match numpy rounding at argmin ties
        const float dx = __fsub_rn(sx, qx);
        const float dy = __fsub_rn(sy, qy);
        const float dz = __fsub_rn(sz, qz);
        const float dd = __fadd_rn(__fadd_rn(__fmul_rn(dx, dx), __fmul_rn(dy, dy)),
                                   __fmul_rn(dz, dz));
        // |kp| < 1.2 strictly => |d| >= 0.9 + 1.2*da implies infl == 0 exactly.
        const float reach = 0.9f + 1.2f * das;
        if (dd < reach * reach) {
            float best = 3.4e38f; int bi = 0;
            #pragma unroll
            for (int k = 0; k < K_P; ++k) {
                const float ex = __fsub_rn(dx, __fmul_rn(kp[k * 3 + 0], das));
                const float ey = __fsub_rn(dy, __fmul_rn(kp[k * 3 + 1], das));
                const float ez = __fsub_rn(dz, __fmul_rn(kp[k * 3 + 2], das));
                const float d2 = __fadd_rn(__fadd_rn(__fmul_rn(ex, ex), __fmul_rn(ey, ey)),
                                           __fmul_rn(ez, ez));
                if (d2 < best) { best = d2; bi = k; }
            }
            const float f = 1.f - sqrtf(best) / 0.9f;
            fl = fmaxf(f, 0.f);
            nn = bi;
        }
    }

    unsigned long long mask = __ballot(fl > 0.f);
    const int c0 = lane << 1;
    float2 acc = {0.f, 0.f};
    while (mask) {
        const int h = __builtin_ctzll(mask);
        mask &= mask - 1;
        const int   ih = __shfl(idx, h);
        const int   nh = __shfl(nn, h);
        const float fh = __shfl(fl, h);
        const float2 fv = *reinterpret_cast<const float2*>(s_feats + (size_t)ih * C_F + c0);
        const float2 wv = *reinterpret_cast<const float2*>(weights + nh * C_F + c0);
        const float  mv = bf16_f(mod[(size_t)r * MODC + nh * 16 + (lane >> 2)]);
        const float  s  = fh * mv;
        acc.x = fmaf(fv.x * wv.x, s, acc.x);
        acc.y = fmaf(fv.y * wv.y, s, acc.y);
    }
    reinterpret_cast<float2*>(out + (size_t)m * C_F)[lane] = acc;
}

// ---------------------------------------------------------------------------
extern "C" void kernel_launch(void* const* d_in, const int* in_sizes, int n_in,
                              void* d_out, int out_size, void* d_ws, size_t ws_size,
                              hipStream_t stream)
{
    const float* q_pts  = (const float*)d_in[0];
    const float* s_pts  = (const float*)d_in[1];
    const float* s_feat = (const float*)d_in[2];
    const int*   nbi    = (const int*)d_in[3];
    const float* da     = (const float*)d_in[4];
    const float* wts    = (const float*)d_in[5];
    const float* w1     = (const float*)d_in[6];
    const float* b1     = (const float*)d_in[7];
    const float* w2     = (const float*)d_in[8];
    const float* kp     = (const float*)d_in[9];
    float* out = (float*)d_out;

    const int M = in_sizes[4];   // da_scale has M elements

    // workspace layout: bf16 transposed weights (92KB, 256B-aligned) then mod (bf16)
    unsigned short* w1t = (unsigned short*)d_ws;
    unsigned short* w2t = w1t + C_F * C_F;
    size_t woff = ((size_t)(C_F * C_F + C_F * MODC) * sizeof(unsigned short) + 255) & ~(size_t)255;
    unsigned short* mod = (unsigned short*)((char*)d_ws + woff);

    const int nsplit = (C_F * C_F + C_F * MODC + 255) / 256;
    split_w_kernel<<<dim3(nsplit), 256, 0, stream>>>(w1, w2, w1t, w2t);

    // mod needs M*240*2 = 24MB; chunk if workspace is smaller.
    size_t cap = (ws_size - woff) / ((size_t)MODC * sizeof(unsigned short));
    int chunk = (cap >= (size_t)M) ? M : (int)(cap & ~(size_t)63);
    if (chunk < 64) chunk = 64;

    for (int m0 = 0; m0 < M; m0 += chunk) {
        int rows = M - m0; if (rows > chunk) rows = chunk;
        const int nchunks = (rows + ROWS_B - 1) / ROWS_B;
        const int grid = nchunks < 256 ? nchunks : 256;
        mlp_kernel<<<dim3(grid), 512, 0, stream>>>(
            s_feat, w1t, w2t, b1, mod, m0, rows);
        kpconv_kernel<<<dim3((rows + 3) / 4), 256, 0, stream>>>(
            q_pts, s_pts, s_feat, nbi, da, wts, kp, mod, out, m0, rows);
    }
}